// Round 6
// baseline (590.906 us; speedup 1.0000x reference)
//
#include <hip/hip_runtime.h>
#include <hip/hip_bf16.h>
#include <math.h>

#define DIMC 1024
#define SEQ  2048
#define BATCH 4
#define NTOK 8192
#define HEADS 16
#define HD 64

typedef __attribute__((ext_vector_type(8))) short short8;
typedef __attribute__((ext_vector_type(4))) float f32x4;

#define GLDS(gp, lp) __builtin_amdgcn_global_load_lds(                        \
    (const __attribute__((address_space(1))) void*)(gp),                      \
    (__attribute__((address_space(3))) void*)(lp), 16, 0, 0)

__device__ __forceinline__ float bf2f(unsigned short u) {
    union { unsigned int i; float f; } v; v.i = ((unsigned int)u) << 16; return v.f;
}
__device__ __forceinline__ unsigned short f2bf(float f) {
    union { float f; unsigned int i; } v; v.f = f;
    unsigned int r = v.i + 0x7FFFu + ((v.i >> 16) & 1u);
    return (unsigned short)(r >> 16);
}
// HW packed f32x2 -> bf16x2 (v_cvt_pk_bf16_f32)
__device__ __forceinline__ unsigned int pk2bf(float a, float b) {
    __hip_bfloat162 h = __float22bfloat162_rn(make_float2(a, b));
    unsigned int u; __builtin_memcpy(&u, &h, 4); return u;
}

// ---------------------------------------------------------------------------
// Fused prep (x4 vectorized): x cvt | 3 pointwise-weight cvts | mask->bias.
// ---------------------------------------------------------------------------
__global__ __launch_bounds__(256)
void prep(const float* __restrict__ x,
          const float* __restrict__ pwq2, const float* __restrict__ pwk2,
          const float* __restrict__ pwv2, const int* __restrict__ mask,
          unsigned short* __restrict__ xb, unsigned short* __restrict__ pq,
          unsigned short* __restrict__ pk, unsigned short* __restrict__ pv,
          float* __restrict__ fb)
{
    const size_t NE = (size_t)NTOK * DIMC;
    const size_t WE = (size_t)DIMC * DIMC;
    size_t i = ((size_t)blockIdx.x * 256 + threadIdx.x) * 4;
    const float* src = nullptr;
    unsigned short* dst = nullptr;
    if (i < NE) { src = x + i; dst = xb + i; }
    else if ((i -= NE) < WE) { src = pwq2 + i; dst = pq + i; }
    else if ((i -= WE) < WE) { src = pwk2 + i; dst = pk + i; }
    else if ((i -= WE) < WE) { src = pwv2 + i; dst = pv + i; }
    else {
        i -= WE;
        int4 m = *(const int4*)(mask + i);
        float4 o;
        o.x = m.x ? 0.0f : -1e30f; o.y = m.y ? 0.0f : -1e30f;
        o.z = m.z ? 0.0f : -1e30f; o.w = m.w ? 0.0f : -1e30f;
        *(float4*)(fb + i) = o;
        return;
    }
    float4 v = *(const float4*)src;
    ushort4 o;
    o.x = f2bf(v.x); o.y = f2bf(v.y); o.z = f2bf(v.z); o.w = f2bf(v.w);
    *(ushort4*)dst = o;
}

// ---------------------------------------------------------------------------
// W [in][out] fp32 -> Wt [out][in] bf16, batched over 4 weights (z)
// ---------------------------------------------------------------------------
__global__ __launch_bounds__(256)
void transpose_cvt4(const float* __restrict__ W0, const float* __restrict__ W1,
                    const float* __restrict__ W2, const float* __restrict__ W3,
                    unsigned short* __restrict__ T0, unsigned short* __restrict__ T1,
                    unsigned short* __restrict__ T2, unsigned short* __restrict__ T3)
{
    int z = blockIdx.z;
    const float* W = z == 0 ? W0 : z == 1 ? W1 : z == 2 ? W2 : W3;
    unsigned short* Wt = z == 0 ? T0 : z == 1 ? T1 : z == 2 ? T2 : T3;
    __shared__ float T[32][33];
    int i0 = blockIdx.y * 32, o0 = blockIdx.x * 32;
    int c = threadIdx.x & 31, r4 = threadIdx.x >> 5;
#pragma unroll
    for (int p = 0; p < 4; ++p) {
        int r = r4 + p * 8;
        T[r][c] = W[(size_t)(i0 + r) * DIMC + o0 + c];
    }
    __syncthreads();
#pragma unroll
    for (int p = 0; p < 4; ++p) {
        int r = r4 + p * 8;
        Wt[(size_t)(o0 + r) * DIMC + i0 + c] = f2bf(T[c][r]);
    }
}

// ---------------------------------------------------------------------------
// bf16 MFMA GEMM core (m97 structure): C = act(A @ Bt^T + bias)
// ---------------------------------------------------------------------------
template<bool SILU, bool F32OUT>
__device__ __forceinline__
void gemm_core(const unsigned short* __restrict__ A,
               const unsigned short* __restrict__ Bt,
               const float* __restrict__ bias, void* __restrict__ Cout)
{
    __shared__ unsigned short As[128 * 32];
    __shared__ unsigned short Bs[128 * 32];
    const int tid = threadIdx.x;
    const int lane = tid & 63;
    const int quad = lane >> 4, l16 = lane & 15;
    const int wave = tid >> 6;
    const int wm = (wave & 1) * 64, wn = (wave >> 1) * 64;
    const int m0 = blockIdx.y * 128, n0 = blockIdx.x * 128;
    const int K = DIMC, N = DIMC;

    f32x4 acc[4][4];
#pragma unroll
    for (int i = 0; i < 4; ++i)
#pragma unroll
        for (int j = 0; j < 4; ++j) acc[i][j] = (f32x4)(0.0f);

    for (int k0 = 0; k0 < K; k0 += 32) {
#pragma unroll
        for (int t = 0; t < 2; ++t) {
            int o = (t * 256 + tid) * 8;
            int row = o >> 5, col = o & 31;
            GLDS(A  + (size_t)(m0 + row) * K + k0 + col, As + o);
            GLDS(Bt + (size_t)(n0 + row) * K + k0 + col, Bs + o);
        }
        __syncthreads();
        short8 af[4], bfb[4];
#pragma unroll
        for (int i = 0; i < 4; ++i)
            af[i] = *(const short8*)(As + (wm + i * 16 + l16) * 32 + quad * 8);
#pragma unroll
        for (int j = 0; j < 4; ++j)
            bfb[j] = *(const short8*)(Bs + (wn + j * 16 + l16) * 32 + quad * 8);
#pragma unroll
        for (int i = 0; i < 4; ++i)
#pragma unroll
            for (int j = 0; j < 4; ++j)
                acc[i][j] = __builtin_amdgcn_mfma_f32_16x16x32_bf16(af[i], bfb[j], acc[i][j], 0, 0, 0);
        __syncthreads();
    }

#pragma unroll
    for (int i = 0; i < 4; ++i) {
        int mrow = m0 + wm + i * 16 + quad * 4;
#pragma unroll
        for (int j = 0; j < 4; ++j) {
            int ncol = n0 + wn + j * 16 + l16;
            float bval = bias[ncol];
#pragma unroll
            for (int r = 0; r < 4; ++r) {
                float v = acc[i][j][r] + bval;
                if (SILU) v = v / (1.0f + __expf(-v));
                if (F32OUT)
                    ((float*)Cout)[(size_t)(mrow + r) * N + ncol] = v;
                else
                    ((unsigned short*)Cout)[(size_t)(mrow + r) * N + ncol] = f2bf(v);
            }
        }
    }
}

__global__ __launch_bounds__(256)
void gemm_qkv(const unsigned short* A,
              const unsigned short* B0, const unsigned short* B1, const unsigned short* B2,
              const float* b0, const float* b1, const float* b2,
              unsigned short* C0, unsigned short* C1, unsigned short* C2)
{
    int z = blockIdx.z;
    gemm_core<true, false>(A, z == 0 ? B0 : z == 1 ? B1 : B2,
                           z == 0 ? b0 : z == 1 ? b1 : b2,
                           z == 0 ? C0 : z == 1 ? C1 : C2);
}

__global__ __launch_bounds__(256)
void gemm_pw(const unsigned short* A0, const unsigned short* A1, const unsigned short* A2,
             const unsigned short* B0, const unsigned short* B1, const unsigned short* B2,
             const float* b0, const float* b1, const float* b2,
             unsigned short* C0, unsigned short* C1, unsigned short* C2)
{
    int z = blockIdx.z;
    gemm_core<false, false>(z == 0 ? A0 : z == 1 ? A1 : A2,
                            z == 0 ? B0 : z == 1 ? B1 : B2,
                            z == 0 ? b0 : z == 1 ? b1 : b2,
                            z == 0 ? C0 : z == 1 ? C1 : C2);
}

__global__ __launch_bounds__(256)
void gemm_wo(const unsigned short* A, const unsigned short* Bt,
             const float* bias, float* C)
{
    gemm_core<false, true>(A, Bt, bias, C);
}

// ---------------------------------------------------------------------------
// Depthwise conv k=3 pad=1 over seq + bias, 8 channels/thread (short8),
// batched over q/k/v (blockIdx.y)
// ---------------------------------------------------------------------------
__global__ __launch_bounds__(256)
void dwconv3(const unsigned short* __restrict__ qb, const unsigned short* __restrict__ kb,
             const unsigned short* __restrict__ vb,
             const float* __restrict__ dwq, const float* __restrict__ dwbq,
             const float* __restrict__ dwk, const float* __restrict__ dwbk,
             const float* __restrict__ dwv, const float* __restrict__ dwbv,
             unsigned short* __restrict__ o0, unsigned short* __restrict__ o1,
             unsigned short* __restrict__ o2)
{
    int z = blockIdx.y;
    const unsigned short* X = z == 0 ? qb : z == 1 ? kb : vb;
    const float* dw  = z == 0 ? dwq  : z == 1 ? dwk  : dwv;
    const float* dwb = z == 0 ? dwbq : z == 1 ? dwbk : dwbv;
    unsigned short* Y = z == 0 ? o0 : z == 1 ? o1 : o2;

    int i8 = (blockIdx.x * 256 + threadIdx.x) * 8;
    int c = i8 & (DIMC - 1);
    int s = (i8 >> 10) & (SEQ - 1);
    short8 zero = {};
    short8 xc8 = *(const short8*)(X + i8);
    short8 xm8 = (s > 0)       ? *(const short8*)(X + i8 - DIMC) : zero;
    short8 xp8 = (s < SEQ - 1) ? *(const short8*)(X + i8 + DIMC) : zero;
    short8 y;
#pragma unroll
    for (int j = 0; j < 8; ++j) {
        float w0 = dw[(c + j) * 3 + 0], w1 = dw[(c + j) * 3 + 1], w2 = dw[(c + j) * 3 + 2];
        float r = fmaf(w0, bf2f((unsigned short)xm8[j]),
                  fmaf(w1, bf2f((unsigned short)xc8[j]),
                  fmaf(w2, bf2f((unsigned short)xp8[j]), dwb[c + j])));
        y[j] = (short)f2bf(r);
    }
    *(short8*)(Y + i8) = y;
}

// ---------------------------------------------------------------------------
// Per-token inverse L2 norms. y=0: q (with 0.125*log2e folded), y=1: k.
// ---------------------------------------------------------------------------
__global__ __launch_bounds__(256)
void rownorms(const unsigned short* __restrict__ qb, const unsigned short* __restrict__ kb,
              float* __restrict__ qsc, float* __restrict__ ksc)
{
    const unsigned short* X = (blockIdx.y ? kb : qb) + (size_t)blockIdx.x * DIMC;
    ushort4 v = ((const ushort4*)X)[threadIdx.x];
    float f0 = bf2f(v.x), f1 = bf2f(v.y), f2 = bf2f(v.z), f3 = bf2f(v.w);
    float s = f0 * f0 + f1 * f1 + f2 * f2 + f3 * f3;
#pragma unroll
    for (int off = 32; off; off >>= 1) s += __shfl_down(s, off, 64);
    __shared__ float part[4];
    if ((threadIdx.x & 63) == 0) part[threadIdx.x >> 6] = s;
    __syncthreads();
    if (threadIdx.x == 0) {
        float tot = part[0] + part[1] + part[2] + part[3];
        float post = blockIdx.y ? 1.0f : 0.125f * 1.44269504088896f;
        float inv = post / fmaxf(sqrtf(tot), 1e-12f);
        (blockIdx.y ? ksc : qsc)[blockIdx.x] = inv;
    }
}

// ---------------------------------------------------------------------------
// V [B,S,C] bf16 -> Vt [B*H][64][SEQ] bf16 (per-head transpose)
// ---------------------------------------------------------------------------
__global__ __launch_bounds__(256)
void vtrans(const unsigned short* __restrict__ V, unsigned short* __restrict__ Vt)
{
    __shared__ unsigned short T[64][65];
    int st = blockIdx.x, bh = blockIdx.y;
    int b = bh >> 4, h = bh & 15;
    int tid = threadIdx.x;
#pragma unroll
    for (int t = 0; t < 16; ++t) {
        int o = t * 256 + tid; int r = o >> 6, c = o & 63;
        T[r][c] = V[(size_t)(b * SEQ + st * 64 + r) * DIMC + h * HD + c];
    }
    __syncthreads();
#pragma unroll
    for (int t = 0; t < 16; ++t) {
        int o = t * 256 + tid; int r = o >> 6, c = o & 63;
        Vt[(size_t)bh * HD * SEQ + (size_t)r * SEQ + st * 64 + c] = T[c][r];
    }
}

// ---------------------------------------------------------------------------
// Attention v5: software-pipelined across k-tiles. Iteration kt issues
// QK(kt) MFMAs (consumed next iteration) then softmax+PV(kt-1) from regs,
// so QK MFMA latency hides under the previous tile's VALU/LDS work.
// Ping-pong register state (A/B) via manual 2x unroll. One barrier/tile.
// ---------------------------------------------------------------------------
struct AttnCtx {
    const float* kscale;
    const float* fbias;
    unsigned short* Pw;
    int quad, l16, bS;     // bS = b*SEQ
    float qsc[2];
    short8 vone;
};

// QK for tile kt from LDS buffer; also grabs V-frags for later PV.
__device__ __forceinline__
void qk_tile(const unsigned short* __restrict__ Ks, const unsigned short* __restrict__ Vs,
             const short8 (&aq)[2][2], int quad, int l16,
             f32x4 (&snew)[2][4], short8 (&cv0)[4], short8 (&cv1)[4])
{
    short8 ak0[4], ak1[4];
#pragma unroll
    for (int t = 0; t < 4; ++t) {
        int row = t * 16 + l16, sw = row & 7;
        ak0[t] = *(const short8*)(Ks + row * 64 + ((quad ^ sw) * 8));
        ak1[t] = *(const short8*)(Ks + row * 64 + (((4 + quad) ^ sw) * 8));
        cv0[t] = *(const short8*)(Vs + row * 64 + ((quad ^ sw) * 8));
        cv1[t] = *(const short8*)(Vs + row * 64 + (((4 + quad) ^ sw) * 8));
    }
#pragma unroll
    for (int sub = 0; sub < 2; ++sub) {
#pragma unroll
        for (int t = 0; t < 4; ++t) {
            f32x4 s = (f32x4)(0.0f);
            s = __builtin_amdgcn_mfma_f32_16x16x32_bf16(ak0[t], aq[sub][0], s, 0, 0, 0);
            s = __builtin_amdgcn_mfma_f32_16x16x32_bf16(ak1[t], aq[sub][1], s, 0, 0, 0);
            snew[sub][t] = s;
        }
    }
}

// softmax + PV + l for tile kt (sacc/V-frags captured in a prior iteration)
__device__ __forceinline__
void soft_pv(const f32x4 (&sacc)[2][4], const short8 (&bv0)[4], const short8 (&bv1)[4],
             int kt, const AttnCtx& cx, f32x4 (&oacc)[2][4], f32x4 (&lacc)[2])
{
    float4 ksv[4], fbv[4];
#pragma unroll
    for (int t = 0; t < 4; ++t) {
        size_t off = (size_t)cx.bS + kt * 64 + t * 16 + cx.quad * 4;
        ksv[t] = *(const float4*)(cx.kscale + off);
        fbv[t] = *(const float4*)(cx.fbias + off);
    }
#pragma unroll
    for (int sub = 0; sub < 2; ++sub) {
        const int prow = sub * 16 + cx.l16;
        const int psw = prow & 7;
        const float qs = cx.qsc[sub];
#pragma unroll
        for (int t = 0; t < 4; ++t) {
            float p0 = exp2f(fmaf(sacc[sub][t][0], qs * ksv[t].x, fbv[t].x));
            float p1 = exp2f(fmaf(sacc[sub][t][1], qs * ksv[t].y, fbv[t].y));
            float p2 = exp2f(fmaf(sacc[sub][t][2], qs * ksv[t].z, fbv[t].z));
            float p3 = exp2f(fmaf(sacc[sub][t][3], qs * ksv[t].w, fbv[t].w));
            uint2 w; w.x = pk2bf(p0, p1); w.y = pk2bf(p2, p3);
            int chunk = (t * 2 + (cx.quad >> 1)) ^ psw;
            *(uint2*)(cx.Pw + prow * 64 + chunk * 8 + (cx.quad & 1) * 4) = w;
        }
    }
#pragma unroll
    for (int sub = 0; sub < 2; ++sub) {
        const int prow = sub * 16 + cx.l16;
        const int psw = prow & 7;
        short8 ap0 = *(const short8*)(cx.Pw + prow * 64 + ((cx.quad ^ psw) * 8));
        short8 ap1 = *(const short8*)(cx.Pw + prow * 64 + (((4 + cx.quad) ^ psw) * 8));
#pragma unroll
        for (int t = 0; t < 4; ++t) {
            oacc[sub][t] = __builtin_amdgcn_mfma_f32_16x16x32_bf16(ap0, bv0[t], oacc[sub][t], 0, 0, 0);
            oacc[sub][t] = __builtin_amdgcn_mfma_f32_16x16x32_bf16(ap1, bv1[t], oacc[sub][t], 0, 0, 0);
        }
        lacc[sub] = __builtin_amdgcn_mfma_f32_16x16x32_bf16(ap0, cx.vone, lacc[sub], 0, 0, 0);
        lacc[sub] = __builtin_amdgcn_mfma_f32_16x16x32_bf16(ap1, cx.vone, lacc[sub], 0, 0, 0);
    }
}

__global__ __launch_bounds__(256)
void attn_mfma5(const unsigned short* __restrict__ Q,
                const unsigned short* __restrict__ Km,
                const unsigned short* __restrict__ Vt,
                const float* __restrict__ qscale,
                const float* __restrict__ kscale,
                const float* __restrict__ fbias,
                unsigned short* __restrict__ O)
{
    __shared__ unsigned short Ksb[2][64 * 64];   // [k][d], chunk-swizzled
    __shared__ unsigned short Vsb[2][64 * 64];   // [d][k], chunk-swizzled
    __shared__ unsigned short Ps[4][32 * 64];    // per-wave [q][k], swizzled
    const int tid = threadIdx.x, lane = tid & 63, wave = tid >> 6;
    const int quad = lane >> 4, l16 = lane & 15;
    const int qt = blockIdx.x, bh = blockIdx.y;
    const int b = bh >> 4, h = bh & 15;
    const size_t qkbase = (size_t)b * SEQ * DIMC + (size_t)h * HD;
    const size_t vtbase = (size_t)bh * HD * SEQ;
    const int qbaseW = qt * 128 + wave * 32;
    const int NT = SEQ / 64;                     // 32 (even)

    AttnCtx cx;
    cx.kscale = kscale; cx.fbias = fbias; cx.Pw = Ps[wave];
    cx.quad = quad; cx.l16 = l16; cx.bS = b * SEQ;
#pragma unroll
    for (int i = 0; i < 8; ++i) cx.vone[i] = (short)0x3F80;

    // Q B-fragments + per-lane q scales: loop-invariant.
    short8 aq[2][2];
#pragma unroll
    for (int sub = 0; sub < 2; ++sub) {
        cx.qsc[sub] = qscale[b * SEQ + qbaseW + sub * 16 + l16];
#pragma unroll
        for (int hf = 0; hf < 2; ++hf)
            aq[sub][hf] = *(const short8*)(Q + qkbase +
                (size_t)(qbaseW + sub * 16 + l16) * DIMC + hf * 32 + quad * 8);
    }

    // staging slot geometry (fixed per thread)
    const int sA = tid,        rA = sA >> 3, cA = (sA & 7) ^ (rA & 7);
    const int sB = 256 + tid,  rB = sB >> 3, cB = (sB & 7) ^ (rB & 7);

#define PREFETCH(kt_, buf_)                                                       \
    do {                                                                          \
        const size_t ko = qkbase + (size_t)(kt_) * 64 * DIMC;                     \
        const size_t vo = vtbase + (size_t)(kt_) * 64;                            \
        GLDS(Km + ko + (size_t)rA * DIMC + cA * 8, Ksb[buf_] + sA * 8);           \
        GLDS(Km + ko + (size_t)rB * DIMC + cB * 8, Ksb[buf_] + sB * 8);           \
        GLDS(Vt + vo + (size_t)rA * SEQ + cA * 8,  Vsb[buf_] + sA * 8);           \
        GLDS(Vt + vo + (size_t)rB * SEQ + cB * 8,  Vsb[buf_] + sB * 8);           \
    } while (0)

    // prologue: stage tile 0 into buffer 0
    PREFETCH(0, 0);

    f32x4 oacc[2][4], lacc[2];
#pragma unroll
    for (int s = 0; s < 2; ++s) {
        lacc[s] = (f32x4)(0.0f);
#pragma unroll
        for (int t = 0; t < 4; ++t) oacc[s][t] = (f32x4)(0.0f);
    }

    f32x4 sSt_A[2][4], sSt_B[2][4];
    short8 vA0[4], vA1[4], vB0[4], vB1[4];

    // kt = 0 (even -> A state, buffer 0)
    __syncthreads();
    PREFETCH(1, 1);
    qk_tile(Ksb[0], Vsb[0], aq, quad, l16, sSt_A, vA0, vA1);

    // pairs (kt odd -> B consume A; kt+1 even -> A consume B), kt = 1..NT-3
    for (int kt = 1; kt < NT - 2; kt += 2) {
        __syncthreads();                 // publish buffer 1 (tile kt)
        PREFETCH(kt + 1, 0);
        qk_tile(Ksb[1], Vsb[1], aq, quad, l16, sSt_B, vB0, vB1);
        soft_pv(sSt_A, vA0, vA1, kt - 1, cx, oacc, lacc);

        __syncthreads();                 // publish buffer 0 (tile kt+1)
        PREFETCH(kt + 2, 1);
        qk_tile(Ksb[0], Vsb[0], aq, quad, l16, sSt_A, vA0, vA1);
        soft_pv(sSt_B, vB0, vB1, kt, cx, oacc, lacc);
    }

    // tail: tile NT-1 (odd -> B), consume A (tile NT-2), then drain B
    __syncthreads();
    qk_tile(Ksb[1], Vsb[1], aq, quad, l16, sSt_B, vB0, vB1);
    soft_pv(sSt_A, vA0, vA1, NT - 2, cx, oacc, lacc);
    soft_pv(sSt_B, vB0, vB1, NT - 1, cx, oacc, lacc);
#undef PREFETCH

    // epilogue: lacc rows match oacc rows exactly -> no shuffles
#pragma unroll
    for (int sub = 0; sub < 2; ++sub)
#pragma unroll
        for (int r = 0; r < 4; ++r) {
            float inv = 1.0f / lacc[sub][r];
            int grow = qbaseW + sub * 16 + quad * 4 + r;
#pragma unroll
            for (int t = 0; t < 4; ++t)
                O[(size_t)(b * SEQ + grow) * DIMC + h * HD + t * 16 + l16] =
                    f2bf(oacc[sub][t][r] * inv);
        }
}

// ---------------------------------------------------------------------------
extern "C" void kernel_launch(void* const* d_in, const int* in_sizes, int n_in,
                              void* d_out, int out_size, void* d_ws, size_t ws_size,
                              hipStream_t stream)
{
    const float* x    = (const float*)d_in[0];
    const int*   mask = (const int*)  d_in[1];
    const float* wq   = (const float*)d_in[2];
    const float* bq   = (const float*)d_in[3];
    const float* dwq  = (const float*)d_in[4];
    const float* dwbq = (const float*)d_in[5];
    const float* pwq  = (const float*)d_in[6];
    const float* pwbq = (const float*)d_in[7];
    const float* wk   = (const float*)d_in[8];
    const float* bk   = (const float*)d_in[9];
    const float* dwk  = (const float*)d_in[10];
    const float* dwbk = (const float*)d_in[11];
    const float* pwk  = (const float*)d_in[12];
    const float* pwbk = (const float*)d_in[13];
    const float* wv   = (const float*)d_in[14];
    const float* bv   = (const float*)d_in[15];
    const float* dwv  = (const float*)d_in[16];
    const float* dwbv = (const float*)d_in[17];
    const float* pwv  = (const float*)d_in[18];
    const float* pwbv = (const float*)d_in[19];
    const float* wo   = (const float*)d_in[20];
    const float* bo   = (const float*)d_in[21];

    float* out = (float*)d_out;
    const size_t NE = (size_t)NTOK * DIMC;
    const size_t WE = (size_t)DIMC * DIMC;
    unsigned short* xb  = (unsigned short*)d_ws;   // x bf16; later dwconv-q out; later attn out
    unsigned short* qb  = xb + NE;
    unsigned short* kb  = qb + NE;
    unsigned short* vb  = kb + NE;
    unsigned short* tbA = vb + NE;
    unsigned short* tbB = tbA + NE;
    unsigned short* vt  = tbB + NE;
    unsigned short* wtq = vt + NE;
    unsigned short* wtk = wtq + WE;
    unsigned short* wtv = wtk + WE;
    unsigned short* wto = wtv + WE;
    unsigned short* pq  = wto + WE;
    unsigned short* pk  = pq + WE;
    unsigned short* pv  = pk + WE;
    float* fbias  = (float*)(pv + WE);
    float* qscale = fbias + NTOK;
    float* kscale = qscale + NTOK;

    const dim3 tgrid(32, 32, 4);
    const dim3 ggrid3(DIMC / 128, NTOK / 128, 3);
    const dim3 ggrid(DIMC / 128, NTOK / 128);
    const dim3 vgrid(SEQ / 64, BATCH * HEADS);
    const dim3 agrid(SEQ / 128, BATCH * HEADS);
    const int pblk = (int)((NE + 3 * WE + NTOK) / 4 / 256);
    const int dblk = (int)(NE / 8 / 256);

    prep<<<pblk, 256, 0, stream>>>(x, pwq, pwk, pwv, mask, xb, pq, pk, pv, fbias);
    transpose_cvt4<<<tgrid, 256, 0, stream>>>(wq, wk, wv, wo, wtq, wtk, wtv, wto);

    // q/k/v = silu(x @ w + b), batched
    gemm_qkv<<<ggrid3, 256, 0, stream>>>(xb, wtq, wtk, wtv, bq, bk, bv, qb, kb, vb);

    // depthwise (batched) -> {xb, tbA, tbB}; pointwise (batched) -> back to q/k/v
    dwconv3<<<dim3(dblk, 3), 256, 0, stream>>>(qb, kb, vb, dwq, dwbq, dwk, dwbk,
                                               dwv, dwbv, xb, tbA, tbB);
    gemm_pw<<<ggrid3, 256, 0, stream>>>(xb, tbA, tbB, pq, pk, pv,
                                        pwbq, pwbk, pwbv, qb, kb, vb);

    // per-token inverse norms (l2norm folded into attention score scaling)
    rownorms<<<dim3(NTOK, 2), 256, 0, stream>>>(qb, kb, qscale, kscale);

    // V transpose, attention (out -> xb), final projection
    vtrans<<<vgrid, 256, 0, stream>>>(vb, vt);
    attn_mfma5<<<agrid, 256, 0, stream>>>(qb, kb, vt, qscale, kscale, fbias, xb);
    gemm_wo<<<ggrid, 256, 0, stream>>>(xb, wto, bo, out);
}

// Round 7
// 536.636 us; speedup vs baseline: 1.1011x; 1.1011x over previous
//
#include <hip/hip_runtime.h>
#include <hip/hip_bf16.h>
#include <math.h>

#define DIMC 1024
#define SEQ  2048
#define BATCH 4
#define NTOK 8192
#define HEADS 16
#define HD 64

typedef __attribute__((ext_vector_type(8))) short short8;
typedef __attribute__((ext_vector_type(4))) float f32x4;
typedef __attribute__((ext_vector_type(16))) float f32x16;

#define GLDS(gp, lp) __builtin_amdgcn_global_load_lds(                        \
    (const __attribute__((address_space(1))) void*)(gp),                      \
    (__attribute__((address_space(3))) void*)(lp), 16, 0, 0)

__device__ __forceinline__ float bf2f(unsigned short u) {
    union { unsigned int i; float f; } v; v.i = ((unsigned int)u) << 16; return v.f;
}
__device__ __forceinline__ unsigned short f2bf(float f) {
    union { float f; unsigned int i; } v; v.f = f;
    unsigned int r = v.i + 0x7FFFu + ((v.i >> 16) & 1u);
    return (unsigned short)(r >> 16);
}
// HW packed f32x2 -> bf16x2 (v_cvt_pk_bf16_f32)
__device__ __forceinline__ unsigned int pk2bf(float a, float b) {
    __hip_bfloat162 h = __float22bfloat162_rn(make_float2(a, b));
    unsigned int u; __builtin_memcpy(&u, &h, 4); return u;
}

// ---------------------------------------------------------------------------
// Fused prep (x4 vectorized): x cvt | 3 pointwise-weight cvts | mask->bias.
// ---------------------------------------------------------------------------
__global__ __launch_bounds__(256)
void prep(const float* __restrict__ x,
          const float* __restrict__ pwq2, const float* __restrict__ pwk2,
          const float* __restrict__ pwv2, const int* __restrict__ mask,
          unsigned short* __restrict__ xb, unsigned short* __restrict__ pq,
          unsigned short* __restrict__ pk, unsigned short* __restrict__ pv,
          float* __restrict__ fb)
{
    const size_t NE = (size_t)NTOK * DIMC;
    const size_t WE = (size_t)DIMC * DIMC;
    size_t i = ((size_t)blockIdx.x * 256 + threadIdx.x) * 4;
    const float* src = nullptr;
    unsigned short* dst = nullptr;
    if (i < NE) { src = x + i; dst = xb + i; }
    else if ((i -= NE) < WE) { src = pwq2 + i; dst = pq + i; }
    else if ((i -= WE) < WE) { src = pwk2 + i; dst = pk + i; }
    else if ((i -= WE) < WE) { src = pwv2 + i; dst = pv + i; }
    else {
        i -= WE;
        int4 m = *(const int4*)(mask + i);
        float4 o;
        o.x = m.x ? 0.0f : -1e30f; o.y = m.y ? 0.0f : -1e30f;
        o.z = m.z ? 0.0f : -1e30f; o.w = m.w ? 0.0f : -1e30f;
        *(float4*)(fb + i) = o;
        return;
    }
    float4 v = *(const float4*)src;
    ushort4 o;
    o.x = f2bf(v.x); o.y = f2bf(v.y); o.z = f2bf(v.z); o.w = f2bf(v.w);
    *(ushort4*)dst = o;
}

// ---------------------------------------------------------------------------
// W [in][out] fp32 -> Wt [out][in] bf16, batched over 4 weights (z)
// ---------------------------------------------------------------------------
__global__ __launch_bounds__(256)
void transpose_cvt4(const float* __restrict__ W0, const float* __restrict__ W1,
                    const float* __restrict__ W2, const float* __restrict__ W3,
                    unsigned short* __restrict__ T0, unsigned short* __restrict__ T1,
                    unsigned short* __restrict__ T2, unsigned short* __restrict__ T3)
{
    int z = blockIdx.z;
    const float* W = z == 0 ? W0 : z == 1 ? W1 : z == 2 ? W2 : W3;
    unsigned short* Wt = z == 0 ? T0 : z == 1 ? T1 : z == 2 ? T2 : T3;
    __shared__ float T[32][33];
    int i0 = blockIdx.y * 32, o0 = blockIdx.x * 32;
    int c = threadIdx.x & 31, r4 = threadIdx.x >> 5;
#pragma unroll
    for (int p = 0; p < 4; ++p) {
        int r = r4 + p * 8;
        T[r][c] = W[(size_t)(i0 + r) * DIMC + o0 + c];
    }
    __syncthreads();
#pragma unroll
    for (int p = 0; p < 4; ++p) {
        int r = r4 + p * 8;
        Wt[(size_t)(o0 + r) * DIMC + i0 + c] = f2bf(T[c][r]);
    }
}

// ---------------------------------------------------------------------------
// bf16 MFMA GEMM core v2: 32x32x16 MFMA, BK=64, XOR-chunk-swizzled LDS.
// C = act(A @ Bt^T + bias). A:[M][K], Bt:[N][K]. 128x128 tile, 4 waves 2x2,
// each wave 64x64 = 2x2 tiles of 32x32. LDS rows of 32 el (64 B), two
// k-halves; chunk (16B) position = cpos ^ (row&3) -> conflict-free b128.
// C/D layout (m74/m101): col=lane&31, row=(reg&3)+8*(reg>>2)+4*(lane>>5).
// ---------------------------------------------------------------------------
template<bool SILU, bool F32OUT>
__device__ __forceinline__
void gemm_core(const unsigned short* __restrict__ A,
               const unsigned short* __restrict__ Bt,
               const float* __restrict__ bias, void* __restrict__ Cout)
{
    __shared__ unsigned short As[2 * 128 * 32];
    __shared__ unsigned short Bs[2 * 128 * 32];
    const int tid = threadIdx.x;
    const int lane = tid & 63;
    const int l32 = lane & 31, hi = lane >> 5;
    const int wave = tid >> 6;
    const int wm = (wave & 1) * 64, wn = (wave >> 1) * 64;
    const int m0 = blockIdx.y * 128, n0 = blockIdx.x * 128;
    const int K = DIMC, N = DIMC;

    f32x16 acc[2][2];
#pragma unroll
    for (int tm = 0; tm < 2; ++tm)
#pragma unroll
        for (int tn = 0; tn < 2; ++tn) acc[tm][tn] = (f32x16)(0.0f);

    // staging geometry: slot s = t*256+tid -> row = s>>2, cpos = s&3;
    // LDS el offset = h*4096 + row*32 + cpos*8; src col = h*32 + (cpos^(row&3))*8
    const int srow = tid >> 2, scp = tid & 3;
    const int srow2 = (256 + tid) >> 2, scp2 = tid & 3;   // t=1: s=256+tid
    const int ssrc  = (scp  ^ (srow  & 3)) * 8;
    const int ssrc2 = (scp2 ^ (srow2 & 3)) * 8;
    const int sld   = srow  * 32 + scp  * 8;
    const int sld2  = srow2 * 32 + scp2 * 8;

    for (int k0 = 0; k0 < K; k0 += 64) {
#pragma unroll
        for (int h = 0; h < 2; ++h) {
            const int hk = k0 + h * 32, hl = h * 4096;
            GLDS(A  + (size_t)(m0 + srow)  * K + hk + ssrc,  As + hl + sld);
            GLDS(A  + (size_t)(m0 + srow2) * K + hk + ssrc2, As + hl + sld2);
            GLDS(Bt + (size_t)(n0 + srow)  * K + hk + ssrc,  Bs + hl + sld);
            GLDS(Bt + (size_t)(n0 + srow2) * K + hk + ssrc2, Bs + hl + sld2);
        }
        __syncthreads();
#pragma unroll
        for (int ks = 0; ks < 4; ++ks) {
            const int h = ks >> 1, cb = (ks & 1) * 2;
            short8 af[2], bf[2];
#pragma unroll
            for (int tm = 0; tm < 2; ++tm) {
                int row = wm + tm * 32 + l32;
                int pos = (cb + hi) ^ (row & 3);
                af[tm] = *(const short8*)(As + h * 4096 + row * 32 + pos * 8);
            }
#pragma unroll
            for (int tn = 0; tn < 2; ++tn) {
                int row = wn + tn * 32 + l32;
                int pos = (cb + hi) ^ (row & 3);
                bf[tn] = *(const short8*)(Bs + h * 4096 + row * 32 + pos * 8);
            }
#pragma unroll
            for (int tm = 0; tm < 2; ++tm)
#pragma unroll
                for (int tn = 0; tn < 2; ++tn)
                    acc[tm][tn] = __builtin_amdgcn_mfma_f32_32x32x16_bf16(
                        af[tm], bf[tn], acc[tm][tn], 0, 0, 0);
        }
        __syncthreads();
    }

#pragma unroll
    for (int tn = 0; tn < 2; ++tn) {
        int ncol = n0 + wn + tn * 32 + l32;
        float bval = bias[ncol];
#pragma unroll
        for (int tm = 0; tm < 2; ++tm) {
#pragma unroll
            for (int r = 0; r < 16; ++r) {
                int mrow = m0 + wm + tm * 32 + (r & 3) + 8 * (r >> 2) + 4 * hi;
                float v = acc[tm][tn][r] + bval;
                if (SILU) v = v / (1.0f + __expf(-v));
                if (F32OUT)
                    ((float*)Cout)[(size_t)mrow * N + ncol] = v;
                else
                    ((unsigned short*)Cout)[(size_t)mrow * N + ncol] = f2bf(v);
            }
        }
    }
}

__global__ __launch_bounds__(256)
void gemm_qkv(const unsigned short* A,
              const unsigned short* B0, const unsigned short* B1, const unsigned short* B2,
              const float* b0, const float* b1, const float* b2,
              unsigned short* C0, unsigned short* C1, unsigned short* C2)
{
    int z = blockIdx.z;
    gemm_core<true, false>(A, z == 0 ? B0 : z == 1 ? B1 : B2,
                           z == 0 ? b0 : z == 1 ? b1 : b2,
                           z == 0 ? C0 : z == 1 ? C1 : C2);
}

__global__ __launch_bounds__(256)
void gemm_pw(const unsigned short* A0, const unsigned short* A1, const unsigned short* A2,
             const unsigned short* B0, const unsigned short* B1, const unsigned short* B2,
             const float* b0, const float* b1, const float* b2,
             unsigned short* C0, unsigned short* C1, unsigned short* C2)
{
    int z = blockIdx.z;
    gemm_core<false, false>(z == 0 ? A0 : z == 1 ? A1 : A2,
                            z == 0 ? B0 : z == 1 ? B1 : B2,
                            z == 0 ? b0 : z == 1 ? b1 : b2,
                            z == 0 ? C0 : z == 1 ? C1 : C2);
}

__global__ __launch_bounds__(256)
void gemm_wo(const unsigned short* A, const unsigned short* Bt,
             const float* bias, float* C)
{
    gemm_core<false, true>(A, Bt, bias, C);
}

// ---------------------------------------------------------------------------
// Depthwise conv k=3 pad=1 over seq + bias, 8 channels/thread (short8),
// batched over q/k/v (blockIdx.y)
// ---------------------------------------------------------------------------
__global__ __launch_bounds__(256)
void dwconv3(const unsigned short* __restrict__ qb, const unsigned short* __restrict__ kb,
             const unsigned short* __restrict__ vb,
             const float* __restrict__ dwq, const float* __restrict__ dwbq,
             const float* __restrict__ dwk, const float* __restrict__ dwbk,
             const float* __restrict__ dwv, const float* __restrict__ dwbv,
             unsigned short* __restrict__ o0, unsigned short* __restrict__ o1,
             unsigned short* __restrict__ o2)
{
    int z = blockIdx.y;
    const unsigned short* X = z == 0 ? qb : z == 1 ? kb : vb;
    const float* dw  = z == 0 ? dwq  : z == 1 ? dwk  : dwv;
    const float* dwb = z == 0 ? dwbq : z == 1 ? dwbk : dwbv;
    unsigned short* Y = z == 0 ? o0 : z == 1 ? o1 : o2;

    int i8 = (blockIdx.x * 256 + threadIdx.x) * 8;
    int c = i8 & (DIMC - 1);
    int s = (i8 >> 10) & (SEQ - 1);
    short8 zero = {};
    short8 xc8 = *(const short8*)(X + i8);
    short8 xm8 = (s > 0)       ? *(const short8*)(X + i8 - DIMC) : zero;
    short8 xp8 = (s < SEQ - 1) ? *(const short8*)(X + i8 + DIMC) : zero;
    short8 y;
#pragma unroll
    for (int j = 0; j < 8; ++j) {
        float w0 = dw[(c + j) * 3 + 0], w1 = dw[(c + j) * 3 + 1], w2 = dw[(c + j) * 3 + 2];
        float r = fmaf(w0, bf2f((unsigned short)xm8[j]),
                  fmaf(w1, bf2f((unsigned short)xc8[j]),
                  fmaf(w2, bf2f((unsigned short)xp8[j]), dwb[c + j])));
        y[j] = (short)f2bf(r);
    }
    *(short8*)(Y + i8) = y;
}

// ---------------------------------------------------------------------------
// Per-token inverse L2 norms. y=0: q (with 0.125*log2e folded), y=1: k.
// ---------------------------------------------------------------------------
__global__ __launch_bounds__(256)
void rownorms(const unsigned short* __restrict__ qb, const unsigned short* __restrict__ kb,
              float* __restrict__ qsc, float* __restrict__ ksc)
{
    const unsigned short* X = (blockIdx.y ? kb : qb) + (size_t)blockIdx.x * DIMC;
    ushort4 v = ((const ushort4*)X)[threadIdx.x];
    float f0 = bf2f(v.x), f1 = bf2f(v.y), f2 = bf2f(v.z), f3 = bf2f(v.w);
    float s = f0 * f0 + f1 * f1 + f2 * f2 + f3 * f3;
#pragma unroll
    for (int off = 32; off; off >>= 1) s += __shfl_down(s, off, 64);
    __shared__ float part[4];
    if ((threadIdx.x & 63) == 0) part[threadIdx.x >> 6] = s;
    __syncthreads();
    if (threadIdx.x == 0) {
        float tot = part[0] + part[1] + part[2] + part[3];
        float post = blockIdx.y ? 1.0f : 0.125f * 1.44269504088896f;
        float inv = post / fmaxf(sqrtf(tot), 1e-12f);
        (blockIdx.y ? ksc : qsc)[blockIdx.x] = inv;
    }
}

// ---------------------------------------------------------------------------
// V [B,S,C] bf16 -> Vt [B*H][64][SEQ] bf16 (per-head transpose)
// ---------------------------------------------------------------------------
__global__ __launch_bounds__(256)
void vtrans(const unsigned short* __restrict__ V, unsigned short* __restrict__ Vt)
{
    __shared__ unsigned short T[64][65];
    int st = blockIdx.x, bh = blockIdx.y;
    int b = bh >> 4, h = bh & 15;
    int tid = threadIdx.x;
#pragma unroll
    for (int t = 0; t < 16; ++t) {
        int o = t * 256 + tid; int r = o >> 6, c = o & 63;
        T[r][c] = V[(size_t)(b * SEQ + st * 64 + r) * DIMC + h * HD + c];
    }
    __syncthreads();
#pragma unroll
    for (int t = 0; t < 16; ++t) {
        int o = t * 256 + tid; int r = o >> 6, c = o & 63;
        Vt[(size_t)bh * HD * SEQ + (size_t)r * SEQ + st * 64 + c] = T[c][r];
    }
}

// ---------------------------------------------------------------------------
// Flash attention v4 (round-5 version, best measured): no-max exp2 softmax
// with l2norm folded as score scaling; l via MFMA-with-ones (C-layout matches
// oacc); HW bf16 pack; S^T MFMA; XOR-swizzled LDS; double-buffered K/V.
// ---------------------------------------------------------------------------
__global__ __launch_bounds__(256)
void attn_mfma4(const unsigned short* __restrict__ Q,
                const unsigned short* __restrict__ Km,
                const unsigned short* __restrict__ Vt,
                const float* __restrict__ qscale,
                const float* __restrict__ kscale,
                const float* __restrict__ fbias,
                unsigned short* __restrict__ O)
{
    __shared__ unsigned short Ksb[2][64 * 64];   // [k][d], chunk-swizzled
    __shared__ unsigned short Vsb[2][64 * 64];   // [d][k], chunk-swizzled
    __shared__ unsigned short Ps[4][32 * 64];    // per-wave [q][k], swizzled
    const int tid = threadIdx.x, lane = tid & 63, wave = tid >> 6;
    const int quad = lane >> 4, l16 = lane & 15;
    const int qt = blockIdx.x, bh = blockIdx.y;
    const int b = bh >> 4, h = bh & 15;
    const size_t qkbase = (size_t)b * SEQ * DIMC + (size_t)h * HD;
    const size_t vtbase = (size_t)bh * HD * SEQ;
    const int qbaseW = qt * 128 + wave * 32;
    const int NT = SEQ / 64;

    // Q B-fragments + per-lane q scales: loop-invariant.
    short8 aq[2][2];
    float qsc[2];
#pragma unroll
    for (int sub = 0; sub < 2; ++sub) {
        qsc[sub] = qscale[b * SEQ + qbaseW + sub * 16 + l16];
#pragma unroll
        for (int hf = 0; hf < 2; ++hf)
            aq[sub][hf] = *(const short8*)(Q + qkbase +
                (size_t)(qbaseW + sub * 16 + l16) * DIMC + hf * 32 + quad * 8);
    }

    short8 vone;
#pragma unroll
    for (int i = 0; i < 8; ++i) vone[i] = (short)0x3F80;   // bf16 1.0

    // staging slot geometry (fixed per thread)
    const int sA = tid,        rA = sA >> 3, cA = (sA & 7) ^ (rA & 7);
    const int sB = 256 + tid,  rB = sB >> 3, cB = (sB & 7) ^ (rB & 7);

    // prologue: stage tile 0 into buffer 0
    GLDS(Km + qkbase + (size_t)rA * DIMC + cA * 8, Ksb[0] + sA * 8);
    GLDS(Km + qkbase + (size_t)rB * DIMC + cB * 8, Ksb[0] + sB * 8);
    GLDS(Vt + vtbase + (size_t)rA * SEQ + cA * 8,  Vsb[0] + sA * 8);
    GLDS(Vt + vtbase + (size_t)rB * SEQ + cB * 8,  Vsb[0] + sB * 8);

    f32x4 oacc[2][4], lacc[2];
#pragma unroll
    for (int s = 0; s < 2; ++s) {
        lacc[s] = (f32x4)(0.0f);
#pragma unroll
        for (int t = 0; t < 4; ++t) oacc[s][t] = (f32x4)(0.0f);
    }

    unsigned short* Pw = Ps[wave];

    for (int kt = 0; kt < NT; ++kt) {
        const int cur = kt & 1;
        __syncthreads();   // publishes buffer `cur`

        if (kt + 1 < NT) {
            const size_t ko = qkbase + (size_t)(kt + 1) * 64 * DIMC;
            const size_t vo = vtbase + (size_t)(kt + 1) * 64;
            GLDS(Km + ko + (size_t)rA * DIMC + cA * 8, Ksb[cur ^ 1] + sA * 8);
            GLDS(Km + ko + (size_t)rB * DIMC + cB * 8, Ksb[cur ^ 1] + sB * 8);
            GLDS(Vt + vo + (size_t)rA * SEQ + cA * 8,  Vsb[cur ^ 1] + sA * 8);
            GLDS(Vt + vo + (size_t)rB * SEQ + cB * 8,  Vsb[cur ^ 1] + sB * 8);
        }

        const unsigned short* Ks = Ksb[cur];
        const unsigned short* Vs = Vsb[cur];

        // K A-frags + V B-frags (swizzled, conflict-free)
        short8 ak0[4], ak1[4], bv0[4], bv1[4];
#pragma unroll
        for (int t = 0; t < 4; ++t) {
            int row = t * 16 + l16, sw = row & 7;
            ak0[t] = *(const short8*)(Ks + row * 64 + ((quad ^ sw) * 8));
            ak1[t] = *(const short8*)(Ks + row * 64 + (((4 + quad) ^ sw) * 8));
            bv0[t] = *(const short8*)(Vs + row * 64 + ((quad ^ sw) * 8));
            bv1[t] = *(const short8*)(Vs + row * 64 + (((4 + quad) ^ sw) * 8));
        }

        // per-k-row scale & mask bias (rows t*16 + quad*4 + r)
        float4 ksv[4], fbv[4];
#pragma unroll
        for (int t = 0; t < 4; ++t) {
            size_t off = (size_t)b * SEQ + kt * 64 + t * 16 + quad * 4;
            ksv[t] = *(const float4*)(kscale + off);
            fbv[t] = *(const float4*)(fbias + off);
        }

#pragma unroll
        for (int sub = 0; sub < 2; ++sub) {
            // S^T tiles: rows k (t*16+quad*4+r), cols q (l16)
            f32x4 sacc[4];
#pragma unroll
            for (int t = 0; t < 4; ++t) sacc[t] = (f32x4)(0.0f);
#pragma unroll
            for (int t = 0; t < 4; ++t) {
                sacc[t] = __builtin_amdgcn_mfma_f32_16x16x32_bf16(ak0[t], aq[sub][0], sacc[t], 0, 0, 0);
                sacc[t] = __builtin_amdgcn_mfma_f32_16x16x32_bf16(ak1[t], aq[sub][1], sacc[t], 0, 0, 0);
            }
            const int prow = sub * 16 + l16;
            const int psw = prow & 7;
            const float qs = qsc[sub];
#pragma unroll
            for (int t = 0; t < 4; ++t) {
                float p0 = exp2f(fmaf(sacc[t][0], qs * ksv[t].x, fbv[t].x));
                float p1 = exp2f(fmaf(sacc[t][1], qs * ksv[t].y, fbv[t].y));
                float p2 = exp2f(fmaf(sacc[t][2], qs * ksv[t].z, fbv[t].z));
                float p3 = exp2f(fmaf(sacc[t][3], qs * ksv[t].w, fbv[t].w));
                uint2 w; w.x = pk2bf(p0, p1); w.y = pk2bf(p2, p3);
                int chunk = (t * 2 + (quad >> 1)) ^ psw;
                *(uint2*)(Pw + prow * 64 + chunk * 8 + (quad & 1) * 4) = w;
            }
        }

        // PV + l: O[q][d] += P@V^T ; l[q] += P@ones (same C-layout as oacc)
#pragma unroll
        for (int sub = 0; sub < 2; ++sub) {
            const int prow = sub * 16 + l16;
            const int psw = prow & 7;
            short8 ap0 = *(const short8*)(Pw + prow * 64 + ((quad ^ psw) * 8));
            short8 ap1 = *(const short8*)(Pw + prow * 64 + (((4 + quad) ^ psw) * 8));
#pragma unroll
            for (int t = 0; t < 4; ++t) {
                oacc[sub][t] = __builtin_amdgcn_mfma_f32_16x16x32_bf16(ap0, bv0[t], oacc[sub][t], 0, 0, 0);
                oacc[sub][t] = __builtin_amdgcn_mfma_f32_16x16x32_bf16(ap1, bv1[t], oacc[sub][t], 0, 0, 0);
            }
            lacc[sub] = __builtin_amdgcn_mfma_f32_16x16x32_bf16(ap0, vone, lacc[sub], 0, 0, 0);
            lacc[sub] = __builtin_amdgcn_mfma_f32_16x16x32_bf16(ap1, vone, lacc[sub], 0, 0, 0);
        }
    }

    // epilogue: lacc rows match oacc rows exactly -> no shuffles
#pragma unroll
    for (int sub = 0; sub < 2; ++sub)
#pragma unroll
        for (int r = 0; r < 4; ++r) {
            float inv = 1.0f / lacc[sub][r];
            int grow = qbaseW + sub * 16 + quad * 4 + r;
#pragma unroll
            for (int t = 0; t < 4; ++t)
                O[(size_t)(b * SEQ + grow) * DIMC + h * HD + t * 16 + l16] =
                    f2bf(oacc[sub][t][r] * inv);
        }
}

// ---------------------------------------------------------------------------
extern "C" void kernel_launch(void* const* d_in, const int* in_sizes, int n_in,
                              void* d_out, int out_size, void* d_ws, size_t ws_size,
                              hipStream_t stream)
{
    const float* x    = (const float*)d_in[0];
    const int*   mask = (const int*)  d_in[1];
    const float* wq   = (const float*)d_in[2];
    const float* bq   = (const float*)d_in[3];
    const float* dwq  = (const float*)d_in[4];
    const float* dwbq = (const float*)d_in[5];
    const float* pwq  = (const float*)d_in[6];
    const float* pwbq = (const float*)d_in[7];
    const float* wk   = (const float*)d_in[8];
    const float* bk   = (const float*)d_in[9];
    const float* dwk  = (const float*)d_in[10];
    const float* dwbk = (const float*)d_in[11];
    const float* pwk  = (const float*)d_in[12];
    const float* pwbk = (const float*)d_in[13];
    const float* wv   = (const float*)d_in[14];
    const float* bv   = (const float*)d_in[15];
    const float* dwv  = (const float*)d_in[16];
    const float* dwbv = (const float*)d_in[17];
    const float* pwv  = (const float*)d_in[18];
    const float* pwbv = (const float*)d_in[19];
    const float* wo   = (const float*)d_in[20];
    const float* bo   = (const float*)d_in[21];

    float* out = (float*)d_out;
    const size_t NE = (size_t)NTOK * DIMC;
    const size_t WE = (size_t)DIMC * DIMC;
    unsigned short* xb  = (unsigned short*)d_ws;   // x bf16; later dwconv-q out; later attn out
    unsigned short* qb  = xb + NE;
    unsigned short* kb  = qb + NE;
    unsigned short* vb  = kb + NE;
    unsigned short* tbA = vb + NE;
    unsigned short* tbB = tbA + NE;
    unsigned short* vt  = tbB + NE;
    unsigned short* wtq = vt + NE;
    unsigned short* wtk = wtq + WE;
    unsigned short* wtv = wtk + WE;
    unsigned short* wto = wtv + WE;
    unsigned short* pq  = wto + WE;
    unsigned short* pk  = pq + WE;
    unsigned short* pv  = pk + WE;
    float* fbias  = (float*)(pv + WE);
    float* qscale = fbias + NTOK;
    float* kscale = qscale + NTOK;

    const dim3 tgrid(32, 32, 4);
    const dim3 ggrid3(DIMC / 128, NTOK / 128, 3);
    const dim3 ggrid(DIMC / 128, NTOK / 128);
    const dim3 vgrid(SEQ / 64, BATCH * HEADS);
    const dim3 agrid(SEQ / 128, BATCH * HEADS);
    const int pblk = (int)((NE + 3 * WE + NTOK) / 4 / 256);
    const int dblk = (int)(NE / 8 / 256);

    prep<<<pblk, 256, 0, stream>>>(x, pwq, pwk, pwv, mask, xb, pq, pk, pv, fbias);
    transpose_cvt4<<<tgrid, 256, 0, stream>>>(wq, wk, wv, wo, wtq, wtk, wtv, wto);

    // q/k/v = silu(x @ w + b), batched
    gemm_qkv<<<ggrid3, 256, 0, stream>>>(xb, wtq, wtk, wtv, bq, bk, bv, qb, kb, vb);

    // depthwise (batched) -> {xb, tbA, tbB}; pointwise (batched) -> back to q/k/v
    dwconv3<<<dim3(dblk, 3), 256, 0, stream>>>(qb, kb, vb, dwq, dwbq, dwk, dwbk,
                                               dwv, dwbv, xb, tbA, tbB);
    gemm_pw<<<ggrid3, 256, 0, stream>>>(xb, tbA, tbB, pq, pk, pv,
                                        pwbq, pwbk, pwbv, qb, kb, vb);

    // per-token inverse norms (l2norm folded into attention score scaling)
    rownorms<<<dim3(NTOK, 2), 256, 0, stream>>>(qb, kb, qscale, kscale);

    // V transpose, attention (out -> xb), final projection
    vtrans<<<vgrid, 256, 0, stream>>>(vb, vt);
    attn_mfma4<<<agrid, 256, 0, stream>>>(qb, kb, vt, qscale, kscale, fbias, xb);
    gemm_wo<<<ggrid, 256, 0, stream>>>(xb, wto, bo, out);
}